// Round 8
// baseline (34.444 us; speedup 1.0000x reference)
//
#include <hip/hip_runtime.h>
#include <hip/hip_bf16.h>
#include <math.h>

// ABMIL gated-attention pooling, one streaming pass over valid rows only.
// a = tanh(x.w1)*sigmoid(x.w2) bounded in (-1,1) -> no softmax max-trick;
// masked rows contribute exactly 0 (exp(-10000) underflows) and are never
// loaded. out = (z@wf^T)/s is linear in z -> each block reduces to
// {pd[4], s} at its block index; finish kernel reduces in fixed order.
// Load balance: 4096 small blocks (16 rows each) -> HW dispatcher
// back-fills CUs as blocks drain. Lessons: R6: no single atomic ticket
// (150us serialization); R5: no __launch_bounds__ min-waves (VGPR cap ->
// spills) and no per-block __threadfence; R3: per-row p is wave-uniform
// post-butterfly -> s is uniform, never wave_reduce it.

#define NB   4
#define NN   16384
#define DD   1024
#define LL   4
#define RPB  16                  // rows per block
#define RPW  4                   // rows per wave (4 waves)
#define GX   (NN / RPB)          // 1024 blocks per bag
#define NBLK (GX * NB)           // 4096 total blocks

struct POut { float pd[LL]; float s; float pad[3]; };  // 32 B

__device__ __forceinline__ float wave_reduce(float v) {
    #pragma unroll
    for (int off = 32; off > 0; off >>= 1) v += __shfl_xor(v, off, 64);
    return v;
}

__device__ __forceinline__ float fast_rcp(float x) {
    return __builtin_amdgcn_rcpf(x);
}

// pop lowest set bit index; -1 if empty (m is wave-uniform -> scalar ops)
__device__ __forceinline__ int popnext(unsigned& m) {
    if (m == 0u) return -1;
    const int i = (int)__builtin_ctz(m);
    m &= m - 1u;
    return i;
}

// ---------------------------------------------------------------------------
// Main: grid (GX, NB), 256 threads (4 waves), 4 rows per wave. Ballot the
// wave's validity bits, depth-2 pipelined loop over ONLY the valid rows,
// project register-z onto wf (global reads, L1/L2-hot), tiny LDS combine,
// write {pd[4], s} to parts[block]. No atomics, no fences.
// ---------------------------------------------------------------------------
__global__ __launch_bounds__(256) void abmil_main(
    const float* __restrict__ xs, const void* __restrict__ valid,
    const float* __restrict__ w1, const float* __restrict__ w2,
    const float* __restrict__ wf, POut* __restrict__ parts) {
    const int blk  = blockIdx.x;
    const int bag  = blockIdx.y;
    const int tid  = threadIdx.x;
    const int wave = tid >> 6;
    const int lane = tid & 63;

    // ---- wave-local dtype detect: 1 load + 2 ballots ----
    // Row 0 of bag 0 is guaranteed valid, so the first 16 words classify:
    // int32 -> all words in {0,1}; f32 -> {0, 1.0f}; else byte(bool).
    const unsigned wd = ((const unsigned*)valid)[lane & 15];
    const unsigned long long bi = __ballot(wd != 0u && wd != 1u);
    const unsigned long long bf = __ballot(wd != 0u && wd != 0x3F800000u);
    const int mode = (bi == 0ull) ? 1 : ((bf == 0ull) ? 2 : 0);

    // ---- gate weights into registers (16 f32/lane each) ----
    const float4* w1v = (const float4*)w1;
    const float4* w2v = (const float4*)w2;
    float4 w1r[4], w2r[4];
    #pragma unroll
    for (int k = 0; k < 4; ++k) {
        w1r[k] = w1v[k * 64 + lane];
        w2r[k] = w2v[k * 64 + lane];
    }

    // ---- validity mask for this wave's 4 rows ----
    const int n0 = blk * RPB + wave * RPW;
    int flag = 0;
    if (lane < RPW) {
        const size_t idx = (size_t)bag * NN + n0 + lane;
        if (mode == 1)      flag = ((const int*)valid)[idx] != 0;
        else if (mode == 2) flag = ((const float*)valid)[idx] != 0.0f;
        else                flag = ((const unsigned char*)valid)[idx] != 0;
    }
    unsigned m = (unsigned)(__ballot(flag) & ((1u << RPW) - 1u));

    // ---- accumulators ----
    float s = 0.0f;   // wave-uniform (p is uniform post-reduce)
    float4 z[4];
    #pragma unroll
    for (int k = 0; k < 4; ++k) z[k] = make_float4(0.f, 0.f, 0.f, 0.f);

    const float4* xbase = (const float4*)(xs + (size_t)bag * NN * DD);

    auto loadrow = [&](float4 (&xr)[4], int idx) {
        if (idx >= 0) {
            const float4* xp = xbase + (size_t)(n0 + idx) * (DD / 4);
            #pragma unroll
            for (int k = 0; k < 4; ++k) xr[k] = xp[k * 64 + lane];
        }
    };
    auto comprow = [&](const float4 (&xr)[4]) {
        float d1 = 0.f, d2 = 0.f;
        #pragma unroll
        for (int k = 0; k < 4; ++k) {
            d1 += xr[k].x * w1r[k].x + xr[k].y * w1r[k].y +
                  xr[k].z * w1r[k].z + xr[k].w * w1r[k].w;
            d2 += xr[k].x * w2r[k].x + xr[k].y * w2r[k].y +
                  xr[k].z * w2r[k].z + xr[k].w * w2r[k].w;
        }
        #pragma unroll
        for (int off = 32; off > 0; off >>= 1) {
            d1 += __shfl_xor(d1, off, 64);
            d2 += __shfl_xor(d2, off, 64);
        }
        // tanh via exp identity (overflow-safe), sigmoid via rcp
        const float e  = __expf(-2.0f * fabsf(d1));
        const float tn = copysignf((1.0f - e) * fast_rcp(1.0f + e), d1);
        const float sg = fast_rcp(1.0f + __expf(-d2));
        const float p  = __expf(tn * sg);
        s += p;
        #pragma unroll
        for (int k = 0; k < 4; ++k) {
            z[k].x += p * xr[k].x; z[k].y += p * xr[k].y;
            z[k].z += p * xr[k].z; z[k].w += p * xr[k].w;
        }
    };

    // ---- depth-2 pipelined loop over valid rows only (<=4) ----
    float4 xA[4], xB[4];
    int iA = popnext(m), iB = popnext(m);
    loadrow(xA, iA); loadrow(xB, iB);
    while (iA >= 0) {
        comprow(xA); iA = popnext(m); loadrow(xA, iA);
        if (iB < 0) break;
        comprow(xB); iB = popnext(m); loadrow(xB, iB);
    }

    // ---- project z onto wf rows (global reads, L1/L2-hot) ----
    const float4* wfv = (const float4*)wf;
    float pl[LL] = {0.f, 0.f, 0.f, 0.f};
    #pragma unroll
    for (int l = 0; l < LL; ++l) {
        #pragma unroll
        for (int k = 0; k < 4; ++k) {
            const float4 wv = wfv[l * 256 + k * 64 + lane];
            pl[l] += z[k].x * wv.x + z[k].y * wv.y +
                     z[k].z * wv.z + z[k].w * wv.w;
        }
    }
    #pragma unroll
    for (int l = 0; l < LL; ++l) pl[l] = wave_reduce(pl[l]);

    // ---- block combine via LDS, single POut store ----
    __shared__ float comb[4][LL];
    __shared__ float scomb[4];
    if (lane == 0) {
        #pragma unroll
        for (int l = 0; l < LL; ++l) comb[wave][l] = pl[l];
        scomb[wave] = s;   // uniform: take directly, NO reduce
    }
    __syncthreads();

    POut* po = &parts[(size_t)bag * GX + blk];
    if (tid < LL)
        po->pd[tid] = comb[0][tid] + comb[1][tid] + comb[2][tid] + comb[3][tid];
    if (tid == LL)
        po->s = scomb[0] + scomb[1] + scomb[2] + scomb[3];
}

// ---------------------------------------------------------------------------
// Finish: grid NB (one block per bag), 256 threads. Each block reduces its
// bag's GX POuts in fixed order: 4 per lane per wave, wave_reduce (lanes
// hold DIFFERENT partials here -> reduce is correct), LDS-combine 4 waves,
// normalize, write out[b*4..b*4+3].
// ---------------------------------------------------------------------------
__global__ __launch_bounds__(256) void abmil_finish(
    const POut* __restrict__ parts, float* __restrict__ out) {
    const int bag  = blockIdx.x;
    const int tid  = threadIdx.x;
    const int wave = tid >> 6;
    const int lane = tid & 63;

    float pd0 = 0.f, pd1 = 0.f, pd2 = 0.f, pd3 = 0.f, s = 0.f;
    #pragma unroll
    for (int j = 0; j < GX / 256; ++j) {   // 4 per thread
        const POut* p = &parts[(size_t)bag * GX + j * 256 + tid];
        pd0 += p->pd[0]; pd1 += p->pd[1];
        pd2 += p->pd[2]; pd3 += p->pd[3];
        s   += p->s;
    }
    pd0 = wave_reduce(pd0); pd1 = wave_reduce(pd1);
    pd2 = wave_reduce(pd2); pd3 = wave_reduce(pd3);
    s   = wave_reduce(s);

    __shared__ float comb[4][LL + 1];
    if (lane == 0) {
        comb[wave][0] = pd0; comb[wave][1] = pd1;
        comb[wave][2] = pd2; comb[wave][3] = pd3;
        comb[wave][4] = s;
    }
    __syncthreads();
    if (tid == 0) {
        const float st = comb[0][4] + comb[1][4] + comb[2][4] + comb[3][4];
        const float r  = 1.0f / st;
        #pragma unroll
        for (int l = 0; l < LL; ++l)
            out[bag * LL + l] =
                (comb[0][l] + comb[1][l] + comb[2][l] + comb[3][l]) * r;
    }
}

// ---------------------------------------------------------------------------
extern "C" void kernel_launch(void* const* d_in, const int* in_sizes, int n_in,
                              void* d_out, int out_size, void* d_ws, size_t ws_size,
                              hipStream_t stream) {
    const float* xs    = (const float*)d_in[0];
    const void*  valid = d_in[1];
    const float* w1    = (const float*)d_in[2];
    const float* w2    = (const float*)d_in[3];
    const float* wf    = (const float*)d_in[4];
    float* out = (float*)d_out;

    POut* parts = (POut*)d_ws;   // NBLK*32 B = 128 KB << ws_size

    dim3 g0(GX, NB);
    abmil_main<<<g0, 256, 0, stream>>>(xs, valid, w1, w2, wf, parts);
    abmil_finish<<<NB, 256, 0, stream>>>(parts, out);
}

// Round 9
// 31.125 us; speedup vs baseline: 1.1066x; 1.1066x over previous
//
#include <hip/hip_runtime.h>
#include <hip/hip_bf16.h>
#include <math.h>

// ABMIL gated-attention pooling, one streaming pass over valid rows only.
// a = tanh(x.w1)*sigmoid(x.w2) bounded in (-1,1) -> no softmax max-trick;
// masked rows contribute exactly 0 (exp(-10000) underflows) and are never
// loaded. out = (z@wf^T)/s is linear in z -> each block reduces to
// {pd[4], s} at its block index (SoA); finish reduces in fixed order.
// Grain: RPB=32 is the measured optimum (R4:64->34.5, R7:32->31.8,
// R8:16->34.4) -- below 32, per-block overhead + empty pipelines dominate.
// Lessons: R6: no single atomic ticket (150us serialization); R5: no
// __launch_bounds__ min-waves (VGPR cap -> spills), no __threadfence;
// R3: p is wave-uniform post-butterfly -> s is uniform, never reduce it.

#define NB   4
#define NN   16384
#define DD   1024
#define LL   4
#define RPB  32                  // rows per block (measured optimum)
#define RPW  8                   // rows per wave (4 waves)
#define GX   (NN / RPB)          // 512 blocks per bag
#define NBLK (GX * NB)           // 2048 total blocks

// SoA parts: [component][bag*GX + blk], components = pd0..pd3, s
#define PCOMP 5

__device__ __forceinline__ float wave_reduce(float v) {
    #pragma unroll
    for (int off = 32; off > 0; off >>= 1) v += __shfl_xor(v, off, 64);
    return v;
}

__device__ __forceinline__ float fast_rcp(float x) {
    return __builtin_amdgcn_rcpf(x);
}

// pop lowest set bit index; -1 if empty (m is wave-uniform -> scalar ops)
__device__ __forceinline__ int popnext(unsigned& m) {
    if (m == 0u) return -1;
    const int i = (int)__builtin_ctz(m);
    m &= m - 1u;
    return i;
}

// ---------------------------------------------------------------------------
// Main: grid (GX, NB), 256 threads (4 waves), 8 rows per wave. Ballot the
// wave's validity bits, depth-2 pipelined loop over ONLY the valid rows,
// project register-z onto wf (global reads, L1/L2-hot), tiny LDS combine,
// write {pd[4], s} to SoA parts. No atomics, no fences.
// ---------------------------------------------------------------------------
__global__ __launch_bounds__(256) void abmil_main(
    const float* __restrict__ xs, const void* __restrict__ valid,
    const float* __restrict__ w1, const float* __restrict__ w2,
    const float* __restrict__ wf, float* __restrict__ parts) {
    const int blk  = blockIdx.x;
    const int bag  = blockIdx.y;
    const int tid  = threadIdx.x;
    const int wave = tid >> 6;
    const int lane = tid & 63;

    // ---- wave-local dtype detect: 1 load + 2 ballots ----
    // Row 0 of bag 0 is guaranteed valid, so the first 16 words classify:
    // int32 -> all words in {0,1}; f32 -> {0, 1.0f}; else byte(bool).
    const unsigned wd = ((const unsigned*)valid)[lane & 15];
    const unsigned long long bi = __ballot(wd != 0u && wd != 1u);
    const unsigned long long bf = __ballot(wd != 0u && wd != 0x3F800000u);
    const int mode = (bi == 0ull) ? 1 : ((bf == 0ull) ? 2 : 0);

    // ---- gate weights into registers (16 f32/lane each) ----
    const float4* w1v = (const float4*)w1;
    const float4* w2v = (const float4*)w2;
    float4 w1r[4], w2r[4];
    #pragma unroll
    for (int k = 0; k < 4; ++k) {
        w1r[k] = w1v[k * 64 + lane];
        w2r[k] = w2v[k * 64 + lane];
    }

    // ---- validity mask for this wave's 8 rows ----
    const int n0 = blk * RPB + wave * RPW;
    int flag = 0;
    if (lane < RPW) {
        const size_t idx = (size_t)bag * NN + n0 + lane;
        if (mode == 1)      flag = ((const int*)valid)[idx] != 0;
        else if (mode == 2) flag = ((const float*)valid)[idx] != 0.0f;
        else                flag = ((const unsigned char*)valid)[idx] != 0;
    }
    unsigned m = (unsigned)(__ballot(flag) & ((1u << RPW) - 1u));

    // ---- accumulators ----
    float s = 0.0f;   // wave-uniform (p is uniform post-reduce)
    float4 z[4];
    #pragma unroll
    for (int k = 0; k < 4; ++k) z[k] = make_float4(0.f, 0.f, 0.f, 0.f);

    const float4* xbase = (const float4*)(xs + (size_t)bag * NN * DD);

    auto loadrow = [&](float4 (&xr)[4], int idx) {
        if (idx >= 0) {
            const float4* xp = xbase + (size_t)(n0 + idx) * (DD / 4);
            #pragma unroll
            for (int k = 0; k < 4; ++k) xr[k] = xp[k * 64 + lane];
        }
    };
    auto comprow = [&](const float4 (&xr)[4]) {
        float d1 = 0.f, d2 = 0.f;
        #pragma unroll
        for (int k = 0; k < 4; ++k) {
            d1 += xr[k].x * w1r[k].x + xr[k].y * w1r[k].y +
                  xr[k].z * w1r[k].z + xr[k].w * w1r[k].w;
            d2 += xr[k].x * w2r[k].x + xr[k].y * w2r[k].y +
                  xr[k].z * w2r[k].z + xr[k].w * w2r[k].w;
        }
        #pragma unroll
        for (int off = 32; off > 0; off >>= 1) {
            d1 += __shfl_xor(d1, off, 64);
            d2 += __shfl_xor(d2, off, 64);
        }
        // tanh via exp identity (overflow-safe), sigmoid via rcp
        const float e  = __expf(-2.0f * fabsf(d1));
        const float tn = copysignf((1.0f - e) * fast_rcp(1.0f + e), d1);
        const float sg = fast_rcp(1.0f + __expf(-d2));
        const float p  = __expf(tn * sg);
        s += p;
        #pragma unroll
        for (int k = 0; k < 4; ++k) {
            z[k].x += p * xr[k].x; z[k].y += p * xr[k].y;
            z[k].z += p * xr[k].z; z[k].w += p * xr[k].w;
        }
    };

    // ---- depth-2 pipelined loop over valid rows only ----
    float4 xA[4], xB[4];
    int iA = popnext(m), iB = popnext(m);
    loadrow(xA, iA); loadrow(xB, iB);
    while (iA >= 0) {
        comprow(xA); iA = popnext(m); loadrow(xA, iA);
        if (iB < 0) break;
        comprow(xB); iB = popnext(m); loadrow(xB, iB);
    }

    // ---- project z onto wf rows (global reads, L1/L2-hot) ----
    const float4* wfv = (const float4*)wf;
    float pl[LL] = {0.f, 0.f, 0.f, 0.f};
    #pragma unroll
    for (int l = 0; l < LL; ++l) {
        #pragma unroll
        for (int k = 0; k < 4; ++k) {
            const float4 wv = wfv[l * 256 + k * 64 + lane];
            pl[l] += z[k].x * wv.x + z[k].y * wv.y +
                     z[k].z * wv.z + z[k].w * wv.w;
        }
    }
    #pragma unroll
    for (int l = 0; l < LL; ++l) pl[l] = wave_reduce(pl[l]);

    // ---- block combine via LDS, 5 SoA stores ----
    __shared__ float comb[4][LL];
    __shared__ float scomb[4];
    if (lane == 0) {
        #pragma unroll
        for (int l = 0; l < LL; ++l) comb[wave][l] = pl[l];
        scomb[wave] = s;   // uniform: take directly, NO reduce
    }
    __syncthreads();

    const size_t pidx = (size_t)bag * GX + blk;
    if (tid < LL)
        parts[(size_t)tid * NBLK + pidx] =
            comb[0][tid] + comb[1][tid] + comb[2][tid] + comb[3][tid];
    if (tid == LL)
        parts[(size_t)LL * NBLK + pidx] =
            scomb[0] + scomb[1] + scomb[2] + scomb[3];
}

// ---------------------------------------------------------------------------
// Finish: grid NB (one block per bag), 256 threads. Coalesced SoA reads
// (2 per thread per component), wave_reduce (lanes hold DIFFERENT partials
// here -> reduce is correct), LDS-combine 4 waves, normalize, write out.
// ---------------------------------------------------------------------------
__global__ __launch_bounds__(256) void abmil_finish(
    const float* __restrict__ parts, float* __restrict__ out) {
    const int bag  = blockIdx.x;
    const int tid  = threadIdx.x;
    const int wave = tid >> 6;
    const int lane = tid & 63;

    float c[PCOMP];
    #pragma unroll
    for (int q = 0; q < PCOMP; ++q) {
        float acc = 0.f;
        #pragma unroll
        for (int j = 0; j < GX / 256; ++j)   // 2 per thread
            acc += parts[(size_t)q * NBLK + (size_t)bag * GX + j * 256 + tid];
        c[q] = wave_reduce(acc);
    }

    __shared__ float comb[4][PCOMP];
    if (lane == 0) {
        #pragma unroll
        for (int q = 0; q < PCOMP; ++q) comb[wave][q] = c[q];
    }
    __syncthreads();
    if (tid == 0) {
        const float st = comb[0][4] + comb[1][4] + comb[2][4] + comb[3][4];
        const float r  = 1.0f / st;
        #pragma unroll
        for (int l = 0; l < LL; ++l)
            out[bag * LL + l] =
                (comb[0][l] + comb[1][l] + comb[2][l] + comb[3][l]) * r;
    }
}

// ---------------------------------------------------------------------------
extern "C" void kernel_launch(void* const* d_in, const int* in_sizes, int n_in,
                              void* d_out, int out_size, void* d_ws, size_t ws_size,
                              hipStream_t stream) {
    const float* xs    = (const float*)d_in[0];
    const void*  valid = d_in[1];
    const float* w1    = (const float*)d_in[2];
    const float* w2    = (const float*)d_in[3];
    const float* wf    = (const float*)d_in[4];
    float* out = (float*)d_out;

    float* parts = (float*)d_ws;   // 5 * 2048 * 4 B = 40 KB << ws_size

    dim3 g0(GX, NB);
    abmil_main<<<g0, 256, 0, stream>>>(xs, valid, w1, w2, wf, parts);
    abmil_finish<<<NB, 256, 0, stream>>>(parts, out);
}